// Round 9
// baseline (370.741 us; speedup 1.0000x reference)
//
#include <hip/hip_runtime.h>
#include <stdint.h>

#define DEVI __device__ __forceinline__

typedef __attribute__((ext_vector_type(8))) short short8;
typedef __attribute__((ext_vector_type(4))) float f32x4;
typedef __attribute__((ext_vector_type(16))) float f32x16;
typedef __attribute__((ext_vector_type(4))) unsigned int u32x4;

static constexpr int Bn = 2;
static constexpr int Tn = 2048;
static constexpr int Cn = 2048;
static constexpr int NH = 16;
static constexpr int HD = 128;
static constexpr int Kdim = 2048;

DEVI unsigned short f2bf(float f) {
  union { float f; unsigned u; } v; v.f = f;
  return (unsigned short)((v.u + 0x7FFFu + ((v.u >> 16) & 1u)) >> 16);
}

DEVI void gload_lds16(const void* g, void* l) {
  __builtin_amdgcn_global_load_lds(
      (const __attribute__((address_space(1))) void*)g,
      (__attribute__((address_space(3))) void*)l, 16, 0, 0);
}

// ---------------- cast fp32 -> bf16 (RNE) ----------------
__global__ __launch_bounds__(256) void cast_bf16_kernel(
    const float* __restrict__ src, unsigned short* __restrict__ dst, int n) {
  int idx = (blockIdx.x * blockDim.x + threadIdx.x) * 4;
  const int stride = gridDim.x * blockDim.x * 4;
  for (; idx < n; idx += stride) {
    f32x4 f = *(const f32x4*)(src + idx);
    unsigned short o[4];
    o[0] = f2bf(f[0]); o[1] = f2bf(f[1]); o[2] = f2bf(f[2]); o[3] = f2bf(f[3]);
    *(unsigned long long*)(dst + idx) = *(const unsigned long long*)o;
  }
}

__global__ __launch_bounds__(256) void cast4_kernel(
    const float* __restrict__ s0, const float* __restrict__ s1,
    const float* __restrict__ s2, const float* __restrict__ s3,
    unsigned short* __restrict__ d0, unsigned short* __restrict__ d1,
    unsigned short* __restrict__ d2, unsigned short* __restrict__ d3, int n) {
  const int w = blockIdx.y;
  const float* src = (w == 0) ? s0 : (w == 1) ? s1 : (w == 2) ? s2 : s3;
  unsigned short* dst = (w == 0) ? d0 : (w == 1) ? d1 : (w == 2) ? d2 : d3;
  int idx = (blockIdx.x * blockDim.x + threadIdx.x) * 4;
  const int stride = gridDim.x * blockDim.x * 4;
  for (; idx < n; idx += stride) {
    f32x4 f = *(const f32x4*)(src + idx);
    unsigned short o[4];
    o[0] = f2bf(f[0]); o[1] = f2bf(f[1]); o[2] = f2bf(f[2]); o[3] = f2bf(f[3]);
    *(unsigned long long*)(dst + idx) = *(const unsigned long long*)o;
  }
}

#define G_BAR() __builtin_amdgcn_s_barrier()
#define G_MFMA(d, a, b) d = __builtin_amdgcn_mfma_f32_16x16x32_bf16(a, b, d, 0, 0, 0)
#define G_MFMA32(d, a, b) d = __builtin_amdgcn_mfma_f32_32x32x16_bf16(a, b, d, 0, 0, 0)

// ---------------- fused QKV GEMM: 256x384, 32x32x16 MFMA, BK=32 ----------
// r8: all 16x16x32 variants pinned at 36-38% MfmaUtil — LDS-bandwidth-bound
// (233 KB LDS traffic per 6.29 MFLOP ≈ 2x the matrix-pipe time). Fix: the
// 32x32x16 MFMA (same 16B/lane operands, 2x FLOPs → 16 vs 8 FLOP per
// operand byte) + fatter wave-tile. Tile 256x384, 8 waves 2Mx4N, wave-tile
// 128x96 (4m x 3n 32x32-frags, acc 12x16=192 regs), BK=32, LDS 80 KB.
// Grid 16x16 = 256 blocks = EXACTLY 1 dispatch round. Traffic: 112 KB rd +
// 40 KB wr per 6.29 MFLOP (1.53x less) → MfmaUtil ceiling ~65%.
// Swizzle (4-chunk rows): phys = logical ^ (row&3) ^ ((row>>2)&3) → ≤2-way
// bank aliasing (free). Ledger: prologue 8 loads, vmcnt(3); per tile ph0
// stages A(t+1) [2], ph1 stages B(t+2) [3]; boundary vmcnt(3) leaves
// exactly B(t+2). B reads (both k-steps) in ph0, B-stage in ph1 — the
// barrier-separated pattern r5 proved race-free.
// C/D layout (m74/m101): n = lane&31, m = (reg&3) + 8*(reg>>2) + 4*(lane>>5).
__global__ __launch_bounds__(512, 2) void gemm_qkv_32x32_kernel(
    const unsigned short* __restrict__ X,
    const unsigned short* __restrict__ W3,
    const float* __restrict__ bq_, const float* __restrict__ bk_, const float* __restrict__ bv_,
    unsigned short* __restrict__ Qo, unsigned short* __restrict__ Ko,
    unsigned short* __restrict__ Vo) {
  constexpr int NT = Kdim / 32;  // 64 K-tiles
  __shared__ unsigned short L[2][20480];  // [A 8192 | B 12288] shorts, 80 KB

  const int tid = threadIdx.x;
  const int wave = tid >> 6, lane = tid & 63;
  const int wm = wave >> 2, wn = wave & 3;   // 2M x 4N
  const int l31 = lane & 31, hi = lane >> 5;

  // XCD-bijective swizzle: 256 = 8 XCDs x 32 contiguous
  const int flat = (int)blockIdx.x + 16 * (int)blockIdx.y;
  const int swz = (flat & 7) * 32 + (flat >> 3);
  const int bx = swz & 15, by = swz >> 4;
  const int n0 = bx * 384;                   // [0, 6144)
  const int m0 = by * 256;

  f32x16 acc[4][3];
  {
    f32x16 z;
#pragma unroll
    for (int k = 0; k < 16; ++k) z[k] = 0.f;
#pragma unroll
    for (int i = 0; i < 4; ++i)
#pragma unroll
      for (int j = 0; j < 3; ++j) acc[i][j] = z;
  }

  // staging: thread -> row tid>>2 (128 rows / 8KB call), phys chunk tid&3;
  // source chunk pre-swizzled: logical = phys ^ swz(row)
  const int srow = tid >> 2;
  const int schunk = (tid & 3) ^ ((tid >> 2) & 3) ^ ((tid >> 4) & 3);
  const unsigned short* Asrc = X + (size_t)(m0 + srow) * Kdim + schunk * 8;
  const unsigned short* Bsrc = W3 + (size_t)(n0 + srow) * Kdim + schunk * 8;

  auto STAGE_A = [&](int buf, int h, int t) {  // rows h*128..h*128+127
    gload_lds16(Asrc + (size_t)(h * 128) * Kdim + t * 32,
                &L[buf][h * 4096 + tid * 8]);
  };
  auto STAGE_B = [&](int buf, int h, int t) {  // rows h*128..h*128+127
    gload_lds16(Bsrc + (size_t)(h * 128) * Kdim + t * 32,
                &L[buf][8192 + h * 4096 + tid * 8]);
  };

  // read swizzle: row&3 == lane&3, (row>>2)&3 == (lane>>2)&3 (bases %32==0)
  const int xorv = (lane & 3) ^ ((lane >> 2) & 3);
  const int pc0 = ((0 + hi) ^ xorv) * 8;   // k-step 0 chunk
  const int pc1 = ((2 + hi) ^ xorv) * 8;   // k-step 1 chunk
  const int arow = (wm * 128 + l31) * 32;
  const int brow = 8192 + (wn * 96 + l31) * 32;
#define RDA(mi, pc) (*(const short8*)&L[cur][arow + (mi) * 1024 + (pc)])
#define RDB(ni, pc) (*(const short8*)&L[cur][brow + (ni) * 1024 + (pc)])

  // prologue: A(0),B(0) -> buf0; B(1) -> buf1; drain all but B(1)'s 3
  STAGE_A(0, 0, 0); STAGE_A(0, 1, 0);
  STAGE_B(0, 0, 0); STAGE_B(0, 1, 0); STAGE_B(0, 2, 0);
  STAGE_B(1, 0, 1); STAGE_B(1, 1, 1); STAGE_B(1, 2, 1);
  asm volatile("s_waitcnt vmcnt(3)" ::: "memory");
  G_BAR();

  short8 Af[4], Bf[3][2];

  for (int t = 0; t < NT; ++t) {
    const int cur = t & 1, nxt = cur ^ 1;
    // ---- ph0: rd A k0 (4) + B k0,k1 (6); stage A(t+1); mfma k0 (12)
#pragma unroll
    for (int m = 0; m < 4; ++m) Af[m] = RDA(m, pc0);
#pragma unroll
    for (int n = 0; n < 3; ++n) { Bf[n][0] = RDB(n, pc0); Bf[n][1] = RDB(n, pc1); }
    if (t + 1 < NT) { STAGE_A(nxt, 0, t + 1); STAGE_A(nxt, 1, t + 1); }
    G_BAR();
    __builtin_amdgcn_s_setprio(1);
#pragma unroll
    for (int m = 0; m < 4; ++m)
#pragma unroll
      for (int n = 0; n < 3; ++n) G_MFMA32(acc[m][n], Af[m], Bf[n][0]);
    __builtin_amdgcn_s_setprio(0);
    G_BAR();
    // ---- ph1: rd A k1 (4); stage B(t+2); mfma k1 (12)
#pragma unroll
    for (int m = 0; m < 4; ++m) Af[m] = RDA(m, pc1);
    if (t + 2 < NT) { STAGE_B(cur, 0, t + 2); STAGE_B(cur, 1, t + 2); STAGE_B(cur, 2, t + 2); }
    G_BAR();
    __builtin_amdgcn_s_setprio(1);
#pragma unroll
    for (int m = 0; m < 4; ++m)
#pragma unroll
      for (int n = 0; n < 3; ++n) G_MFMA32(acc[m][n], Af[m], Bf[n][1]);
    __builtin_amdgcn_s_setprio(0);
    if (t < NT - 2) { asm volatile("s_waitcnt vmcnt(3)" ::: "memory"); }
    else            { asm volatile("s_waitcnt vmcnt(0)" ::: "memory"); }
    G_BAR();
  }
#undef RDA
#undef RDB

  // ---- epilogue: 32x32 C/D layout; route per 32-wide n-frag ----
#pragma unroll
  for (int ni = 0; ni < 3; ++ni) {
    const int n = n0 + wn * 96 + ni * 32 + l31;
    const int mat = n >> 11;           // uniform per frag (32 | 2048)
    const int nl = n & 2047;
    const int h = nl >> 7, d = nl & 127;
    const float bv = (mat == 0 ? bq_ : mat == 1 ? bk_ : bv_)[nl];
    if (mat == 2) {
      // V^T: regs rq*4..rq*4+3 are 4 consecutive m (=t) -> 8B stores
#pragma unroll
      for (int mi = 0; mi < 4; ++mi) {
#pragma unroll
        for (int rq = 0; rq < 4; ++rq) {
          const int m = m0 + wm * 128 + mi * 32 + rq * 8 + hi * 4;
          const int b = m >> 11, tt = m & 2047;
          unsigned short o4[4];
#pragma unroll
          for (int r = 0; r < 4; ++r) o4[r] = f2bf(acc[mi][ni][rq * 4 + r] + bv);
          *(unsigned long long*)&Vo[(((size_t)(b * NH + h)) * HD + d) * Tn + tt] =
              *(const unsigned long long*)o4;
        }
      }
    } else {
      unsigned short* Out = (mat == 0) ? Qo : Ko;
#pragma unroll
      for (int mi = 0; mi < 4; ++mi) {
#pragma unroll
        for (int rq = 0; rq < 4; ++rq) {
#pragma unroll
          for (int r = 0; r < 4; ++r) {
            const int m = m0 + wm * 128 + mi * 32 + rq * 8 + hi * 4 + r;
            const int b = m >> 11, tt = m & 2047;
            Out[(((size_t)(b * NH + h)) * Tn + tt) * HD + d] =
                f2bf(acc[mi][ni][rq * 4 + r] + bv);
          }
        }
      }
    }
  }
}

// ---------------- output projection GEMM (fp32 out), 256x128 ----------------
// (unchanged from r8 passing version; grid 256 blocks = 1 exact round)
__global__ __launch_bounds__(512, 2) void gemm_proj_256x128_kernel(
    const unsigned short* __restrict__ Aall,
    const unsigned short* __restrict__ Wp_,
    const float* __restrict__ bias,
    float* __restrict__ Y) {
  constexpr int NT = Kdim / 64;
  __shared__ unsigned short L[2][24576];

  const int tid = threadIdx.x;
  const int wave = tid >> 6, lane = tid & 63;
  const int wm = wave >> 2, wn = wave & 3;
  const int quad = lane >> 4, lr = lane & 15;

  const int flat = (int)blockIdx.x + 16 * (int)blockIdx.y;
  const int swz = (flat & 7) * 16 + (flat >> 3);
  const int bx = swz % 16, by = swz / 16;
  const int m0 = by * 256, n0 = bx * 128;
  const int bz = blockIdx.z;
  const unsigned short* A = Aall + (size_t)bz * Cn * Tn;

  f32x4 acc[8][2];
  const f32x4 zero4 = {0.f, 0.f, 0.f, 0.f};
#pragma unroll
  for (int i = 0; i < 8; ++i)
#pragma unroll
    for (int j = 0; j < 2; ++j) acc[i][j] = zero4;

  const int srow = tid >> 3;
  const int schunk = (tid & 7) ^ (srow & 7);
  const unsigned short* Asrc = A + (size_t)(m0 + srow) * Kdim + schunk * 8;
  const unsigned short* Bsrc = Wp_ + (size_t)(n0 + srow) * Kdim + schunk * 8;

  auto STAGE_A = [&](int buf, int h, int t) {
    unsigned short* d = &L[buf][h * 8192 + tid * 8];
    const unsigned short* s = Asrc + (size_t)(h * 128) * Kdim + t * 64;
    gload_lds16(s, d);
    gload_lds16(s + (size_t)64 * Kdim, d + 4096);
  };
  auto STAGE_B = [&](int buf, int t) {
    unsigned short* d = &L[buf][16384 + tid * 8];
    const unsigned short* s = Bsrc + t * 64;
    gload_lds16(s, d);
    gload_lds16(s + (size_t)64 * Kdim, d + 4096);
  };

  const int pc0 = quad ^ (lr & 7);
  const int pc1 = (4 + quad) ^ (lr & 7);
  const int aoff = (wm * 128 + lr) * 64;
  const int boff = 16384 + (wn * 32 + lr) * 64;

  STAGE_A(0, 0, 0); STAGE_A(0, 1, 0);
  STAGE_B(0, 0);
  STAGE_B(1, 1);
  asm volatile("s_waitcnt vmcnt(2)" ::: "memory");
  G_BAR();

  short8 Af[4][2], Bf[2][2];

  for (int t = 0; t < NT; ++t) {
    const int cur = t & 1, nxt = cur ^ 1;
#pragma unroll
    for (int m = 0; m < 4; ++m) {
      Af[m][0] = *(const short8*)&L[cur][aoff + m * 1024 + pc0 * 8];
      Af[m][1] = *(const short8*)&L[cur][aoff + m * 1024 + pc1 * 8];
    }
#pragma unroll
    for (int n = 0; n < 2; ++n) {
      Bf[n][0] = *(const short8*)&L[cur][boff + n * 1024 + pc0 * 8];
      Bf[n][1] = *(const short8*)&L[cur][boff + n * 1024 + pc1 * 8];
    }
    if (t + 1 < NT) STAGE_A(nxt, 0, t + 1);
    G_BAR();
    __builtin_amdgcn_s_setprio(1);
#pragma unroll
    for (int m = 0; m < 4; ++m)
#pragma unroll
      for (int n = 0; n < 2; ++n) {
        G_MFMA(acc[m][n], Af[m][0], Bf[n][0]);
        G_MFMA(acc[m][n], Af[m][1], Bf[n][1]);
      }
    __builtin_amdgcn_s_setprio(0);
    G_BAR();
#pragma unroll
    for (int m = 0; m < 4; ++m) {
      Af[m][0] = *(const short8*)&L[cur][aoff + (m + 4) * 1024 + pc0 * 8];
      Af[m][1] = *(const short8*)&L[cur][aoff + (m + 4) * 1024 + pc1 * 8];
    }
    if (t + 1 < NT) STAGE_A(nxt, 1, t + 1);
    if (t + 2 < NT) STAGE_B(cur, t + 2);
    G_BAR();
    __builtin_amdgcn_s_setprio(1);
#pragma unroll
    for (int m = 0; m < 4; ++m)
#pragma unroll
      for (int n = 0; n < 2; ++n) {
        G_MFMA(acc[m + 4][n], Af[m][0], Bf[n][0]);
        G_MFMA(acc[m + 4][n], Af[m][1], Bf[n][1]);
      }
    __builtin_amdgcn_s_setprio(0);
    if (t < NT - 2) { asm volatile("s_waitcnt vmcnt(2)" ::: "memory"); }
    else            { asm volatile("s_waitcnt vmcnt(0)" ::: "memory"); }
    G_BAR();
  }

#pragma unroll
  for (int ni = 0; ni < 2; ++ni) {
    const int n = n0 + wn * 32 + ni * 16 + lr;
    const float bv = bias[n];
#pragma unroll
    for (int mi = 0; mi < 8; ++mi) {
#pragma unroll
      for (int r = 0; r < 4; ++r) {
        const int m = m0 + wm * 128 + mi * 16 + quad * 4 + r;
        Y[((size_t)bz * Tn + m) * Cn + n] = acc[mi][ni][r] + bv;
      }
    }
  }
}

// ---------------- flash attention: 8-wave kv-split (r8 passing version) ---
__global__ __launch_bounds__(512, 2) void attn_kernel(
    const unsigned short* __restrict__ Q,
    const unsigned short* __restrict__ K,
    const unsigned short* __restrict__ V,
    unsigned short* __restrict__ Ot) {
  constexpr int KST = 136;
  constexpr int VST = 136;   // 144 x 136 (rows 128..143 = ones)
  constexpr int PST = 136;   // 128 x 136 (4 bands x 32 rows)
  __shared__ unsigned short SMEM[54400];   // 108.8 KB
  unsigned short* Ks = SMEM;               // 128*136 = 17408
  unsigned short* Vs = SMEM + 17408;       // 144*136 = 19584
  unsigned short* Ps = SMEM + 36992;       // 128*136 = 17408

  const int tid = threadIdx.x;
  const int wave = tid >> 6, lane = tid & 63;
  const int wb = wave & 3;                 // q band
  const int wh = wave >> 2;                // kv half
  const int quad = lane >> 4, lr = lane & 15;
  const int bh = blockIdx.y;
  const float SL = 0.08838834764831845f * 1.4426950408889634f;  // scale*log2(e)

  const unsigned short* Kp = K + (size_t)bh * Tn * HD;
  const unsigned short* Vp = V + (size_t)bh * HD * Tn;
  unsigned short* Pw = &Ps[wb * 32 * PST];

  const int r = tid >> 2;
  const int cc = (tid & 3) * 32;
  unsigned short* kl = &Ks[r * KST + cc];
  unsigned short* vl = &Vs[r * VST + cc];
  u32x4 kreg[4], vreg[4];

  const f32x4 zero4 = {0.f, 0.f, 0.f, 0.f};
#pragma unroll 1
  for (int half = 0; half < 2; ++half) {
    const int jt = half ? (15 - (int)blockIdx.x) : (int)blockIdx.x;
    const int q0 = jt * 128;

    // re-init V "ones" rows each half (cbuf clobbers them in the combine)
    for (int i = tid; i < 16 * VST; i += 512) Vs[128 * VST + i] = 0x3F80;

    const unsigned short* Qp = Q + ((size_t)bh * Tn + q0 + wb * 32) * HD;
    short8 qf[2][4];
#pragma unroll
    for (int mi = 0; mi < 2; ++mi)
#pragma unroll
      for (int ks = 0; ks < 4; ++ks)
        qf[mi][ks] = *(const short8*)&Qp[(mi * 16 + lr) * HD + ks * 32 + quad * 8];

    f32x4 oacc[2][9];
#pragma unroll
    for (int mi = 0; mi < 2; ++mi)
#pragma unroll
      for (int nd = 0; nd < 9; ++nd) oacc[mi][nd] = zero4;

    const int nch = q0 / 128 + 1;

    {
      const unsigned short* kg = &Kp[(size_t)r * HD + cc];
      const unsigned short* vg = &Vp[(size_t)r * Tn + cc];
#pragma unroll
      for (int p = 0; p < 4; ++p) {
        kreg[p] = *(const u32x4*)(kg + p * 8);
        vreg[p] = *(const u32x4*)(vg + p * 8);
      }
    }

    for (int c = 0; c < nch; ++c) {
      const int k0 = c * 128;
#pragma unroll
      for (int p = 0; p < 4; ++p) {
        *(u32x4*)(kl + p * 8) = kreg[p];
        *(u32x4*)(vl + p * 8) = vreg[p];
      }
      __syncthreads();
      if (c + 1 < nch) {
        const int k1 = k0 + 128;
        const unsigned short* kg = &Kp[(size_t)(k1 + r) * HD + cc];
        const unsigned short* vg = &Vp[(size_t)r * Tn + k1 + cc];
#pragma unroll
        for (int p = 0; p < 4; ++p) {
          kreg[p] = *(const u32x4*)(kg + p * 8);
          vreg[p] = *(const u32x4*)(vg + p * 8);
        }
      }

      // QK^T for this wave's nt half (4 of 8 16-col tiles)
      f32x4 sa[2][4];
#pragma unroll
      for (int mi = 0; mi < 2; ++mi)
#pragma unroll
        for (int n4 = 0; n4 < 4; ++n4) sa[mi][n4] = zero4;
#pragma unroll
      for (int n4 = 0; n4 < 4; ++n4) {
        const int nt = wh * 4 + n4;
        short8 kf[4];
#pragma unroll
        for (int ks = 0; ks < 4; ++ks)
          kf[ks] = *(const short8*)&Ks[(nt * 16 + lr) * KST + ks * 32 + quad * 8];
#pragma unroll
        for (int mi = 0; mi < 2; ++mi)
#pragma unroll
          for (int ks = 0; ks < 4; ++ks)
            sa[mi][n4] = __builtin_amdgcn_mfma_f32_16x16x32_bf16(qf[mi][ks], kf[ks], sa[mi][n4], 0, 0, 0);
      }

      if (k0 == q0) {
#pragma unroll
        for (int mi = 0; mi < 2; ++mi)
#pragma unroll
          for (int n4 = 0; n4 < 4; ++n4)
#pragma unroll
            for (int r2 = 0; r2 < 4; ++r2) {
              const int qg = q0 + wb * 32 + mi * 16 + quad * 4 + r2;
              const int kg = k0 + (wh * 4 + n4) * 16 + lr;
              if (kg > qg) sa[mi][n4][r2] = -3.0e38f;
            }
      }

#pragma unroll
      for (int mi = 0; mi < 2; ++mi)
#pragma unroll
        for (int n4 = 0; n4 < 4; ++n4)
#pragma unroll
          for (int r2 = 0; r2 < 4; ++r2) {
            const float p = __builtin_amdgcn_exp2f(sa[mi][n4][r2] * SL);
            Pw[(mi * 16 + quad * 4 + r2) * PST + (wh * 4 + n4) * 16 + lr] = f2bf(p);
          }

      // PV over this wave's kt half (2 of 4 32-col k-slices) — intra-wave P
#pragma unroll
      for (int k2 = 0; k2 < 2; ++k2) {
        const int kt = wh * 2 + k2;
        short8 pf[2];
#pragma unroll
        for (int mi = 0; mi < 2; ++mi)
          pf[mi] = *(const short8*)&Pw[(mi * 16 + lr) * PST + kt * 32 + quad * 8];
#pragma unroll
        for (int nd = 0; nd < 9; ++nd) {
          short8 vf = *(const short8*)&Vs[(nd * 16 + lr) * VST + kt * 32 + quad * 8];
#pragma unroll
          for (int mi = 0; mi < 2; ++mi)
            oacc[mi][nd] = __builtin_amdgcn_mfma_f32_16x16x32_bf16(pf[mi], vf, oacc[mi][nd], 0, 0, 0);
        }
      }
      __syncthreads();
    }

    // ---- combine kv-partials: wh==1 publish to LDS (overlays dead Ks/Vs)
    f32x4* cbuf = (f32x4*)SMEM;   // 4608 x 16B = 73728 B (clobbers ones rows)
    if (wh == 1) {
#pragma unroll
      for (int mi = 0; mi < 2; ++mi)
#pragma unroll
        for (int nd = 0; nd < 9; ++nd)
          cbuf[(wb * 64 + lane) * 18 + mi * 9 + nd] = oacc[mi][nd];
    }
    __syncthreads();
    if (wh == 0) {
#pragma unroll
      for (int mi = 0; mi < 2; ++mi)
#pragma unroll
        for (int nd = 0; nd < 9; ++nd)
          oacc[mi][nd] += cbuf[(wb * 64 + lane) * 18 + mi * 9 + nd];
      // normalize + stage into Ps (t-major)
#pragma unroll
      for (int mi = 0; mi < 2; ++mi)
#pragma unroll
        for (int r2 = 0; r2 < 4; ++r2) {
          const float rl = 1.0f / oacc[mi][8][r2];
          const int tl = wb * 32 + mi * 16 + quad * 4 + r2;
#pragma unroll
          for (int nd = 0; nd < 8; ++nd)
            Ps[tl * PST + nd * 16 + lr] = f2bf(oacc[mi][nd][r2] * rl);
        }
    }
    __syncthreads();
    if (tid < 256) {
      unsigned short* Od = Ot + (size_t)bh * HD * Tn + q0;  // row = d, stride Tn
#pragma unroll
      for (int p = 0; p < 8; ++p) {
        const int d = p * 16 + (tid >> 4);
        const int t8 = (tid & 15) * 8;
        alignas(16) unsigned short v[8];
#pragma unroll
        for (int j = 0; j < 8; ++j) v[j] = Ps[(t8 + j) * PST + d];
        *(u32x4*)&Od[(size_t)d * Tn + t8] = *(const u32x4*)v;
      }
    }
    __syncthreads();
  }
}

extern "C" void kernel_launch(void* const* d_in, const int* in_sizes, int n_in,
                              void* d_out, int out_size, void* d_ws, size_t ws_size,
                              hipStream_t stream) {
  const float* x  = (const float*)d_in[0];
  const float* Wq = (const float*)d_in[1];
  const float* bq = (const float*)d_in[2];
  const float* Wk = (const float*)d_in[3];
  const float* bk = (const float*)d_in[4];
  const float* Wv = (const float*)d_in[5];
  const float* bv = (const float*)d_in[6];
  const float* Wp = (const float*)d_in[7];
  const float* bp = (const float*)d_in[8];
  float* out = (float*)d_out;

  char* ws = (char*)d_ws;
  const size_t MB = 1ull << 20;
  unsigned short* Xbf = (unsigned short*)(ws);             // 16MB
  unsigned short* Wqb = (unsigned short*)(ws + 16 * MB);   // 8MB each; Wq/Wk/Wv
  unsigned short* Wkb = (unsigned short*)(ws + 24 * MB);   //  CONTIGUOUS = W3
  unsigned short* Wvb = (unsigned short*)(ws + 32 * MB);
  unsigned short* Wpb = (unsigned short*)(ws + 40 * MB);
  unsigned short* Qb  = (unsigned short*)(ws + 48 * MB);   // 16MB
  unsigned short* Kb  = (unsigned short*)(ws + 64 * MB);   // 16MB
  unsigned short* Vtb = (unsigned short*)(ws + 80 * MB);   // 16MB (B,H,D,T)
  unsigned short* Otb = (unsigned short*)(ws + 96 * MB);   // 16MB (B,H*D,T)

  cast_bf16_kernel<<<dim3(1024), dim3(256), 0, stream>>>(x, Xbf, Bn * Tn * Cn);
  cast4_kernel<<<dim3(512, 4), dim3(256), 0, stream>>>(
      Wq, Wk, Wv, Wp, Wqb, Wkb, Wvb, Wpb, Cn * Cn);

  gemm_qkv_32x32_kernel<<<dim3(16, 16), dim3(512), 0, stream>>>(
      Xbf, Wqb /* = W3 base */, bq, bk, bv, Qb, Kb, Vtb);

  attn_kernel<<<dim3(8, Bn * NH), dim3(512), 0, stream>>>(Qb, Kb, Vtb, Otb);

  gemm_proj_256x128_kernel<<<dim3(16, 8, 2), dim3(512), 0, stream>>>(
      Otb, Wpb, bp, out);
}